// Round 17
// baseline (208.140 us; speedup 1.0000x reference)
//
#include <hip/hip_runtime.h>
#include <math.h>

// ClusterisedSelfAttentionNotLearnable — R21 (resubmit; container infra
// failure, third occurrence of the signature that passed on unchanged
// resubmit in Rounds 1 and 11): R18 body + persistent-wave grid-stride loop
// (the residency-vs-contention discriminator).
// R20 post-mortem: block-shared-LDS B == per-wave-L2 B == 56-57us. Load
// latency falsified as the bottleneck. Conservation: 302 wave-us/CU over
// 57us -> avg residency 5.3 waves/CU, identical across all structures; if
// the allowed 16/CU were resident, duration would be ~25us. Either a slot/
// dispatch limiter caps residency (~5/CU) or co-resident waves contend.
// R21 removes dispatch from the equation: 2048 one-wave blocks (8 wg/CU),
// each grid-striding over ~3 point-blocks with the UNCHANGED R18 body.
// If slot-limited: occ -> 22-26%, dur -> 40-46us. If contention: flat ~57
// -> declare practical plateau. Tripwires: VGPR<=130, WRITE 2.34MB.

#define NCLUST   256
#define M_BLK    32
#define THREADS  64
#define NTILES   15
#define PERSIST_BLOCKS 2048
#define BG_BYTES (NTILES * 8 * 64 * 16)   // 122880
#define ET_STRIDE 72                       // bytes/e-row: 32 pts * 2B + 8B pad

typedef __attribute__((ext_vector_type(8))) short bfrag_t;        // 8 bf16
typedef __attribute__((ext_vector_type(4))) float cfrag_t;        // 4 f32
typedef __attribute__((ext_vector_type(4))) unsigned int uifrag_t; // A-frag storage

static __device__ __forceinline__ unsigned short f2bf1(float f) {
    return __builtin_bit_cast(unsigned short, (__bf16)f);   // RNE, v_cvt_pk_bf16_f32
}
static __device__ __forceinline__ unsigned int f2bf2(float lo, float hi) {
    return (unsigned int)f2bf1(lo) | ((unsigned int)f2bf1(hi) << 16);
}
static __device__ __forceinline__ float bf2f(unsigned short s) {
    return __uint_as_float(((unsigned int)s) << 16);
}

// Build W' in fragment order: unit u -> (tile=u>>9, ks=(u>>6)&7, lane=u&63),
// lane=(q=lane>>4, ln=lane&15); holds W'[j'=tile*16+ln][c=ks*32+q*8 .. +8].
// W'[j'][c] = (e<72) ? W[(c*3+d)*72+e] : 0, with d=j'/80, e=j'-80d.
__global__ void prep_kernel(const float* __restrict__ W, uint4* __restrict__ Bg) {
    const int u = blockIdx.x * 256 + threadIdx.x;
    if (u >= NTILES * 8 * 64) return;
    const int lane = u & 63, ks = (u >> 6) & 7, tile = u >> 9;
    const int ln = lane & 15, q = lane >> 4;
    const int jp = tile * 16 + ln;
    const int d  = jp / 80;
    const int e  = jp - d * 80;
    const int c0 = ks * 32 + q * 8;
    unsigned int w[4] = {0u, 0u, 0u, 0u};
    if (e < 72) {
#pragma unroll
        for (int i = 0; i < 4; ++i) {
            float f0 = W[((c0 + 2 * i)     * 3 + d) * 72 + e];
            float f1 = W[((c0 + 2 * i + 1) * 3 + d) * 72 + e];
            w[i] = f2bf2(f0, f1);
        }
    }
    Bg[u] = make_uint4(w[0], w[1], w[2], w[3]);
}

#define MFMA2(KS, B) \
    a0 = __builtin_amdgcn_mfma_f32_16x16x32_bf16( \
             __builtin_bit_cast(bfrag_t, afrag[0][KS]), (B), a0, 0, 0, 0); \
    a1 = __builtin_amdgcn_mfma_f32_16x16x32_bf16( \
             __builtin_bit_cast(bfrag_t, afrag[1][KS]), (B), a1, 0, 0, 0);

__global__ __launch_bounds__(THREADS, 2) void rgb_attn_mfma(
    const float* __restrict__ X,
    const float* __restrict__ cent,
    const void* __restrict__ Bg,
    float* __restrict__ out, int N)
{
    __shared__ __align__(16) float Xs[M_BLK * 6];                 // 768 B, staged X
    __shared__ __align__(16) unsigned char encT[80 * ET_STRIDE];  // 5760 B, [e][point]

    const int lane = threadIdx.x;          // one wave per block
    const int q    = lane >> 4;
    const int ln   = lane & 15;
    const int nPB  = (N + M_BLK - 1) / M_BLK;
    const char* Bgc = (const char*)Bg + lane * 16;

#pragma unroll 1
    for (int pb = blockIdx.x; pb < nPB; pb += PERSIST_BLOCKS) {
        const int mbase = pb * M_BLK;

        // ---- stage X coalesced FIRST (its vmcnt wait precedes the B loads) ----
        if (mbase + M_BLK <= N) {
            if (lane < 48) {
                const float4 v = *(const float4*)(X + (size_t)mbase * 6 + lane * 4);
                *(float4*)(Xs + lane * 4) = v;
            }
        } else {
#pragma unroll 1
            for (int i = lane; i < M_BLK * 6; i += 64) {
                const int p  = mbase + i / 6;
                const int pc = (p < N) ? p : (N - 1);
                Xs[i] = X[pc * 6 + (i % 6)];
            }
        }

        // ---- B tile 0 into the 8 rolling slots: hides under the prologue ----
        bfrag_t b0 = *(const bfrag_t*)(Bgc + 0 * 1024);
        bfrag_t b1 = *(const bfrag_t*)(Bgc + 1 * 1024);
        bfrag_t b2 = *(const bfrag_t*)(Bgc + 2 * 1024);
        bfrag_t b3 = *(const bfrag_t*)(Bgc + 3 * 1024);
        bfrag_t b4 = *(const bfrag_t*)(Bgc + 4 * 1024);
        bfrag_t b5 = *(const bfrag_t*)(Bgc + 5 * 1024);
        bfrag_t b6 = *(const bfrag_t*)(Bgc + 6 * 1024);
        bfrag_t b7 = *(const bfrag_t*)(Bgc + 7 * 1024);

        // ---- positional encoding into encT (transposed): 2 thr/point, 3 dims ----
        {
            const int pt = lane & 31;
            const int h  = lane >> 5;
            unsigned char* colp = encT + pt * 2;
#pragma unroll
            for (int k = 0; k < 3; ++k) {
                const int dd = 3 * h + k;
                const float xv = Xs[pt * 6 + dd];
                float s[6], c[6];
                __sincosf(xv, &s[0], &c[0]);
#pragma unroll
                for (int f = 1; f < 6; ++f) {        // exact double-angle identities
                    s[f] = 2.0f * s[f-1] * c[f-1];
                    c[f] = 1.0f - 2.0f * s[f-1] * s[f-1];
                }
#pragma unroll
                for (int f = 0; f < 6; ++f) {
                    *(unsigned short*)(colp + (dd*12 + f)     * ET_STRIDE) = f2bf1(s[f]);
                    *(unsigned short*)(colp + (dd*12 + 6 + f) * ET_STRIDE) = f2bf1(c[f]);
                }
            }
            // zero pad rows e in [72,80): 8 rows x 64B, 8 threads/row x 8B
            *(uint2*)(encT + (72 + (lane >> 3)) * ET_STRIDE + (lane & 7) * 8) =
                make_uint2(0u, 0u);
        }

        // ---- attention: A-fragments directly in registers (verified lane map) --
        // Lane (q,ln) feeds MFMA rows mt*16+ln with clusters 32*g + q*8 + {0..7}.
        uifrag_t afrag[2][8];
        float dA = 0.0f, dB = 0.0f;
        {
            const float x00 = Xs[ln * 6 + 0], x01 = Xs[ln * 6 + 1], x02 = Xs[ln * 6 + 2];
            const float x10 = Xs[(16 + ln) * 6 + 0], x11 = Xs[(16 + ln) * 6 + 1],
                        x12 = Xs[(16 + ln) * 6 + 2];
            const float4* c4base = (const float4*)cent;
#pragma unroll
            for (int g = 0; g < 8; ++g) {
                // 8 cent rows 32g + q*8 .. +8  ==  6 aligned float4
                const float4* c4 = c4base + (6 * q + 24 * g);
                const float4 v0 = c4[0], v1 = c4[1], v2 = c4[2];
                const float4 v3 = c4[3], v4 = c4[4], v5 = c4[5];
                float cx[8], cy[8], cz[8];
                cx[0]=v0.x; cy[0]=v0.y; cz[0]=v0.z;
                cx[1]=v0.w; cy[1]=v1.x; cz[1]=v1.y;
                cx[2]=v1.z; cy[2]=v1.w; cz[2]=v2.x;
                cx[3]=v2.y; cy[3]=v2.z; cz[3]=v2.w;
                cx[4]=v3.x; cy[4]=v3.y; cz[4]=v3.z;
                cx[5]=v3.w; cy[5]=v4.x; cz[5]=v4.y;
                cx[6]=v4.z; cy[6]=v4.w; cz[6]=v5.x;
                cx[7]=v5.y; cy[7]=v5.z; cz[7]=v5.w;
                float ea[8], eb[8];
#pragma unroll
                for (int j = 0; j < 8; ++j) {
                    ea[j] = __expf(fmaf(x00, cx[j], fmaf(x01, cy[j], x02 * cz[j])));
                    eb[j] = __expf(fmaf(x10, cx[j], fmaf(x11, cy[j], x12 * cz[j])));
                    dA += ea[j]; dB += eb[j];
                }
#pragma unroll
                for (int w = 0; w < 4; ++w) {
                    afrag[0][g][w] = f2bf2(ea[2*w], ea[2*w+1]);
                    afrag[1][g][w] = f2bf2(eb[2*w], eb[2*w+1]);
                }
            }
        }

        // ---- main loop: 3 d-groups (unrolled), 5-tile inner loop ROLLED.
        //      Rolling B slots (reload after last use, ~200cy cover). ----
#pragma unroll
        for (int d = 0; d < 3; ++d) {
            float part2[2][4] = {};
#pragma unroll 1
            for (int tt = 0; tt < 5; ++tt) {
                const int t = d * 5 + tt;
                const char* bp = Bgc + (t + 1) * 8192;
                cfrag_t a0 = {0.f,0.f,0.f,0.f}, a1 = {0.f,0.f,0.f,0.f};

                // stage A: consume b0..b3, then reload them with tile t+1
                MFMA2(0, b0) MFMA2(1, b1) MFMA2(2, b2) MFMA2(3, b3)
                if (t < NTILES - 1) {
                    b0 = *(const bfrag_t*)(bp + 0 * 1024);
                    b1 = *(const bfrag_t*)(bp + 1 * 1024);
                    b2 = *(const bfrag_t*)(bp + 2 * 1024);
                    b3 = *(const bfrag_t*)(bp + 3 * 1024);
                }

                // stage B: consume b4..b7, then reload them with tile t+1
                MFMA2(4, b4) MFMA2(5, b5) MFMA2(6, b6) MFMA2(7, b7)
                if (t < NTILES - 1) {
                    b4 = *(const bfrag_t*)(bp + 4 * 1024);
                    b5 = *(const bfrag_t*)(bp + 5 * 1024);
                    b6 = *(const bfrag_t*)(bp + 6 * 1024);
                    b7 = *(const bfrag_t*)(bp + 7 * 1024);
                }

                // epilogue: enc-weighted accumulation
                const unsigned char* ep = encT + (tt * 16 + ln) * ET_STRIDE + q * 8;
#pragma unroll
                for (int mt = 0; mt < 2; ++mt) {
                    const ushort4 ev = *(const ushort4*)(ep + mt * 32);
                    const cfrag_t a = mt ? a1 : a0;
                    part2[mt][0] = fmaf(a[0], bf2f(ev.x), part2[mt][0]);
                    part2[mt][1] = fmaf(a[1], bf2f(ev.y), part2[mt][1]);
                    part2[mt][2] = fmaf(a[2], bf2f(ev.z), part2[mt][2]);
                    part2[mt][3] = fmaf(a[3], bf2f(ev.w), part2[mt][3]);
                }
            }

            // ---- d-group epilogue: reduce over the 16 e-lanes ----
#pragma unroll
            for (int mask = 1; mask <= 8; mask <<= 1)
#pragma unroll
                for (int mt = 0; mt < 2; ++mt)
#pragma unroll
                    for (int r = 0; r < 4; ++r)
                        part2[mt][r] += __shfl_xor(part2[mt][r], mask, 64);

            // denominators (recomputed per group from persistent dA/dB)
            float sA = dA + __shfl_xor(dA, 16, 64); sA += __shfl_xor(sA, 32, 64);
            float sB = dB + __shfl_xor(dB, 16, 64); sB += __shfl_xor(sB, 32, 64);
            const float iA = 1.0f / sA;          // denom of point ln (all q-lanes)
            const float iB = 1.0f / sB;          // denom of point 16+ln
            float invr[2][4];
#pragma unroll
            for (int r = 0; r < 4; ++r) {        // lane q*4+r: denom of point q*4+r
                invr[0][r] = __shfl(iA, q * 4 + r, 64);
                invr[1][r] = __shfl(iB, q * 4 + r, 64);
            }

            if (ln == 0) {
#pragma unroll
                for (int mt = 0; mt < 2; ++mt)
#pragma unroll
                    for (int r = 0; r < 4; ++r) {
                        const int pm = mt * 16 + q * 4 + r;
                        const int g  = mbase + pm;
                        if (g < N)
                            out[g * 3 + d] = part2[mt][r] * invr[mt][r];
                    }
            }
        }
    }
}

// ---- fallback (correct, slow) if d_ws too small ----
__global__ __launch_bounds__(256) void rgb_attn_fallback(
    const float* __restrict__ X, const float* __restrict__ W,
    const float* __restrict__ cent, float* __restrict__ out, int N)
{
    const int n = blockIdx.x * 256 + threadIdx.x;
    const bool valid = (n < N);
    float x[6];
#pragma unroll
    for (int k = 0; k < 6; ++k) x[k] = valid ? X[n * 6 + k] : 0.0f;
    float enc[72];
#pragma unroll
    for (int d = 0; d < 6; ++d)
#pragma unroll
        for (int f = 0; f < 6; ++f) {
            float s, c;
            __sincosf(x[d] * (float)(1 << f), &s, &c);
            enc[d*12+f] = s; enc[d*12+6+f] = c;
        }
    float acc0 = 0, acc1 = 0, acc2 = 0, denom = 0;
#pragma unroll 1
    for (int c = 0; c < NCLUST; ++c) {
        float s = fmaf(x[0], cent[c*3], fmaf(x[1], cent[c*3+1], x[2]*cent[c*3+2]));
        float ew = __expf(s);
        const float* w = W + c * 216;
        float d0 = 0, d1 = 0, d2 = 0;
#pragma unroll
        for (int e = 0; e < 72; ++e) {
            float ee = enc[e];
            d0 = fmaf(ee, w[e], d0);
            d1 = fmaf(ee, w[72 + e], d1);
            d2 = fmaf(ee, w[144 + e], d2);
        }
        denom += ew;
        acc0 = fmaf(ew, d0, acc0); acc1 = fmaf(ew, d1, acc1); acc2 = fmaf(ew, d2, acc2);
    }
    if (valid) {
        float inv = 1.0f / denom;
        out[n*3+0] = acc0*inv; out[n*3+1] = acc1*inv; out[n*3+2] = acc2*inv;
    }
}

extern "C" void kernel_launch(void* const* d_in, const int* in_sizes, int n_in,
                              void* d_out, int out_size, void* d_ws, size_t ws_size,
                              hipStream_t stream)
{
    const float* X    = (const float*)d_in[0];   // [N, 6]
    const float* W    = (const float*)d_in[1];   // [768, 72]
    const float* cent = (const float*)d_in[2];   // [256, 3]
    float* out = (float*)d_out;                  // [N, 3]
    const int N = in_sizes[0] / 6;

    if (ws_size >= (size_t)BG_BYTES) {
        uint4* Bg = (uint4*)d_ws;
        prep_kernel<<<(NTILES * 8 * 64 + 255) / 256, 256, 0, stream>>>(W, Bg);
        const int nPB = (N + M_BLK - 1) / M_BLK;
        const int blocks = (nPB < PERSIST_BLOCKS) ? nPB : PERSIST_BLOCKS;
        rgb_attn_mfma<<<blocks, THREADS, 0, stream>>>(X, cent, (const void*)Bg, out, N);
    } else {
        rgb_attn_fallback<<<(N + 255) / 256, 256, 0, stream>>>(X, W, cent, out, N);
    }
}

// Round 18
// 106.044 us; speedup vs baseline: 1.9628x; 1.9628x over previous
//
#include <hip/hip_runtime.h>
#include <math.h>

// ClusterisedSelfAttentionNotLearnable — R22: persistent R18, spill-proofed.
// R21 post-mortem: the grid-stride loop spilled (WRITE 159MB) because the
// loop body's tile-0 B loads and cent float4 loads have loop-invariant
// addresses -> LICM hoisted them across the back edge, blowing the 128 cap.
// BUT occupancy rose 17.4->19.6% (only config ever to exceed 17.4%):
// persistence DOES lift residency; spill buried it. R22 closes both hoist
// channels: (1) compiler memory fence at loop top (blocks LICM; cent/B
// reloads are L1 hits, same as R18); (2) B-slot carry with wrap-reload —
// tile-0 loads issue once pre-loop; in-loop reload is unconditional with
// tn=(t+1==15)?0:t+1, so after t=14 the slots refill with tile 0 for the
// NEXT pb under the ~2us enc/attention cover. No loop-invariant loads
// remain; demand == R18's proven <=128.
// Tripwires: VGPR<=128, WRITE 2.34MB. Predict occ 22-26%, dur 38-48us;
// flat ~57 with clean counters => contention proven => plateau, revert R18.

#define NCLUST   256
#define M_BLK    32
#define THREADS  64
#define NTILES   15
#define PERSIST_BLOCKS 2048
#define BG_BYTES (NTILES * 8 * 64 * 16)   // 122880
#define ET_STRIDE 72                       // bytes/e-row: 32 pts * 2B + 8B pad

typedef __attribute__((ext_vector_type(8))) short bfrag_t;        // 8 bf16
typedef __attribute__((ext_vector_type(4))) float cfrag_t;        // 4 f32
typedef __attribute__((ext_vector_type(4))) unsigned int uifrag_t; // A-frag storage

static __device__ __forceinline__ unsigned short f2bf1(float f) {
    return __builtin_bit_cast(unsigned short, (__bf16)f);   // RNE, v_cvt_pk_bf16_f32
}
static __device__ __forceinline__ unsigned int f2bf2(float lo, float hi) {
    return (unsigned int)f2bf1(lo) | ((unsigned int)f2bf1(hi) << 16);
}
static __device__ __forceinline__ float bf2f(unsigned short s) {
    return __uint_as_float(((unsigned int)s) << 16);
}

// Build W' in fragment order: unit u -> (tile=u>>9, ks=(u>>6)&7, lane=u&63),
// lane=(q=lane>>4, ln=lane&15); holds W'[j'=tile*16+ln][c=ks*32+q*8 .. +8].
// W'[j'][c] = (e<72) ? W[(c*3+d)*72+e] : 0, with d=j'/80, e=j'-80d.
__global__ void prep_kernel(const float* __restrict__ W, uint4* __restrict__ Bg) {
    const int u = blockIdx.x * 256 + threadIdx.x;
    if (u >= NTILES * 8 * 64) return;
    const int lane = u & 63, ks = (u >> 6) & 7, tile = u >> 9;
    const int ln = lane & 15, q = lane >> 4;
    const int jp = tile * 16 + ln;
    const int d  = jp / 80;
    const int e  = jp - d * 80;
    const int c0 = ks * 32 + q * 8;
    unsigned int w[4] = {0u, 0u, 0u, 0u};
    if (e < 72) {
#pragma unroll
        for (int i = 0; i < 4; ++i) {
            float f0 = W[((c0 + 2 * i)     * 3 + d) * 72 + e];
            float f1 = W[((c0 + 2 * i + 1) * 3 + d) * 72 + e];
            w[i] = f2bf2(f0, f1);
        }
    }
    Bg[u] = make_uint4(w[0], w[1], w[2], w[3]);
}

#define MFMA2(KS, B) \
    a0 = __builtin_amdgcn_mfma_f32_16x16x32_bf16( \
             __builtin_bit_cast(bfrag_t, afrag[0][KS]), (B), a0, 0, 0, 0); \
    a1 = __builtin_amdgcn_mfma_f32_16x16x32_bf16( \
             __builtin_bit_cast(bfrag_t, afrag[1][KS]), (B), a1, 0, 0, 0);

__global__ __launch_bounds__(THREADS, 2) void rgb_attn_mfma(
    const float* __restrict__ X,
    const float* __restrict__ cent,
    const void* __restrict__ Bg,
    float* __restrict__ out, int N)
{
    __shared__ __align__(16) float Xs[M_BLK * 6];                 // 768 B, staged X
    __shared__ __align__(16) unsigned char encT[80 * ET_STRIDE];  // 5760 B, [e][point]

    const int lane = threadIdx.x;          // one wave per block
    const int q    = lane >> 4;
    const int ln   = lane & 15;
    const int nPB  = (N + M_BLK - 1) / M_BLK;
    const char* Bgc = (const char*)Bg + lane * 16;

    // ---- B tile 0 into the 8 rolling slots ONCE; carried across pb iters ----
    bfrag_t b0 = *(const bfrag_t*)(Bgc + 0 * 1024);
    bfrag_t b1 = *(const bfrag_t*)(Bgc + 1 * 1024);
    bfrag_t b2 = *(const bfrag_t*)(Bgc + 2 * 1024);
    bfrag_t b3 = *(const bfrag_t*)(Bgc + 3 * 1024);
    bfrag_t b4 = *(const bfrag_t*)(Bgc + 4 * 1024);
    bfrag_t b5 = *(const bfrag_t*)(Bgc + 5 * 1024);
    bfrag_t b6 = *(const bfrag_t*)(Bgc + 6 * 1024);
    bfrag_t b7 = *(const bfrag_t*)(Bgc + 7 * 1024);

#pragma unroll 1
    for (int pb = blockIdx.x; pb < nPB; pb += PERSIST_BLOCKS) {
        // Compiler fence: no loop-invariant load hoisting across the back
        // edge (R21's spill cause). cent/X reloads below are L1 hits.
        asm volatile("" ::: "memory");

        const int mbase = pb * M_BLK;

        // ---- stage X coalesced FIRST (its vmcnt wait precedes B reloads) ----
        if (mbase + M_BLK <= N) {
            if (lane < 48) {
                const float4 v = *(const float4*)(X + (size_t)mbase * 6 + lane * 4);
                *(float4*)(Xs + lane * 4) = v;
            }
        } else {
#pragma unroll 1
            for (int i = lane; i < M_BLK * 6; i += 64) {
                const int p  = mbase + i / 6;
                const int pc = (p < N) ? p : (N - 1);
                Xs[i] = X[pc * 6 + (i % 6)];
            }
        }

        // ---- positional encoding into encT (transposed): 2 thr/point, 3 dims ----
        {
            const int pt = lane & 31;
            const int h  = lane >> 5;
            unsigned char* colp = encT + pt * 2;
#pragma unroll
            for (int k = 0; k < 3; ++k) {
                const int dd = 3 * h + k;
                const float xv = Xs[pt * 6 + dd];
                float s[6], c[6];
                __sincosf(xv, &s[0], &c[0]);
#pragma unroll
                for (int f = 1; f < 6; ++f) {        // exact double-angle identities
                    s[f] = 2.0f * s[f-1] * c[f-1];
                    c[f] = 1.0f - 2.0f * s[f-1] * s[f-1];
                }
#pragma unroll
                for (int f = 0; f < 6; ++f) {
                    *(unsigned short*)(colp + (dd*12 + f)     * ET_STRIDE) = f2bf1(s[f]);
                    *(unsigned short*)(colp + (dd*12 + 6 + f) * ET_STRIDE) = f2bf1(c[f]);
                }
            }
            // zero pad rows e in [72,80): 8 rows x 64B, 8 threads/row x 8B
            *(uint2*)(encT + (72 + (lane >> 3)) * ET_STRIDE + (lane & 7) * 8) =
                make_uint2(0u, 0u);
        }

        // ---- attention: A-fragments directly in registers (verified lane map) --
        // Lane (q,ln) feeds MFMA rows mt*16+ln with clusters 32*g + q*8 + {0..7}.
        uifrag_t afrag[2][8];
        float dA = 0.0f, dB = 0.0f;
        {
            const float x00 = Xs[ln * 6 + 0], x01 = Xs[ln * 6 + 1], x02 = Xs[ln * 6 + 2];
            const float x10 = Xs[(16 + ln) * 6 + 0], x11 = Xs[(16 + ln) * 6 + 1],
                        x12 = Xs[(16 + ln) * 6 + 2];
            const float4* c4base = (const float4*)cent;
#pragma unroll
            for (int g = 0; g < 8; ++g) {
                // 8 cent rows 32g + q*8 .. +8  ==  6 aligned float4
                const float4* c4 = c4base + (6 * q + 24 * g);
                const float4 v0 = c4[0], v1 = c4[1], v2 = c4[2];
                const float4 v3 = c4[3], v4 = c4[4], v5 = c4[5];
                float cx[8], cy[8], cz[8];
                cx[0]=v0.x; cy[0]=v0.y; cz[0]=v0.z;
                cx[1]=v0.w; cy[1]=v1.x; cz[1]=v1.y;
                cx[2]=v1.z; cy[2]=v1.w; cz[2]=v2.x;
                cx[3]=v2.y; cy[3]=v2.z; cz[3]=v2.w;
                cx[4]=v3.x; cy[4]=v3.y; cz[4]=v3.z;
                cx[5]=v3.w; cy[5]=v4.x; cz[5]=v4.y;
                cx[6]=v4.z; cy[6]=v4.w; cz[6]=v5.x;
                cx[7]=v5.y; cy[7]=v5.z; cz[7]=v5.w;
                float ea[8], eb[8];
#pragma unroll
                for (int j = 0; j < 8; ++j) {
                    ea[j] = __expf(fmaf(x00, cx[j], fmaf(x01, cy[j], x02 * cz[j])));
                    eb[j] = __expf(fmaf(x10, cx[j], fmaf(x11, cy[j], x12 * cz[j])));
                    dA += ea[j]; dB += eb[j];
                }
#pragma unroll
                for (int w = 0; w < 4; ++w) {
                    afrag[0][g][w] = f2bf2(ea[2*w], ea[2*w+1]);
                    afrag[1][g][w] = f2bf2(eb[2*w], eb[2*w+1]);
                }
            }
        }

        // ---- main loop: 3 d-groups (unrolled), 5-tile inner loop ROLLED.
        //      Rolling B slots; reload is UNCONDITIONAL with wrap (t=14
        //      refills tile 0 for the next pb under the prologue cover). ----
#pragma unroll
        for (int d = 0; d < 3; ++d) {
            float part2[2][4] = {};
#pragma unroll 1
            for (int tt = 0; tt < 5; ++tt) {
                const int t  = d * 5 + tt;
                const int tn = (t + 1 == NTILES) ? 0 : (t + 1);
                const char* bp = Bgc + tn * 8192;
                cfrag_t a0 = {0.f,0.f,0.f,0.f}, a1 = {0.f,0.f,0.f,0.f};

                // stage A: consume b0..b3, then reload them with tile tn
                MFMA2(0, b0) MFMA2(1, b1) MFMA2(2, b2) MFMA2(3, b3)
                b0 = *(const bfrag_t*)(bp + 0 * 1024);
                b1 = *(const bfrag_t*)(bp + 1 * 1024);
                b2 = *(const bfrag_t*)(bp + 2 * 1024);
                b3 = *(const bfrag_t*)(bp + 3 * 1024);

                // stage B: consume b4..b7, then reload them with tile tn
                MFMA2(4, b4) MFMA2(5, b5) MFMA2(6, b6) MFMA2(7, b7)
                b4 = *(const bfrag_t*)(bp + 4 * 1024);
                b5 = *(const bfrag_t*)(bp + 5 * 1024);
                b6 = *(const bfrag_t*)(bp + 6 * 1024);
                b7 = *(const bfrag_t*)(bp + 7 * 1024);

                // epilogue: enc-weighted accumulation
                const unsigned char* ep = encT + (tt * 16 + ln) * ET_STRIDE + q * 8;
#pragma unroll
                for (int mt = 0; mt < 2; ++mt) {
                    const ushort4 ev = *(const ushort4*)(ep + mt * 32);
                    const cfrag_t a = mt ? a1 : a0;
                    part2[mt][0] = fmaf(a[0], bf2f(ev.x), part2[mt][0]);
                    part2[mt][1] = fmaf(a[1], bf2f(ev.y), part2[mt][1]);
                    part2[mt][2] = fmaf(a[2], bf2f(ev.z), part2[mt][2]);
                    part2[mt][3] = fmaf(a[3], bf2f(ev.w), part2[mt][3]);
                }
            }

            // ---- d-group epilogue: reduce over the 16 e-lanes ----
#pragma unroll
            for (int mask = 1; mask <= 8; mask <<= 1)
#pragma unroll
                for (int mt = 0; mt < 2; ++mt)
#pragma unroll
                    for (int r = 0; r < 4; ++r)
                        part2[mt][r] += __shfl_xor(part2[mt][r], mask, 64);

            // denominators (recomputed per group from persistent dA/dB)
            float sA = dA + __shfl_xor(dA, 16, 64); sA += __shfl_xor(sA, 32, 64);
            float sB = dB + __shfl_xor(dB, 16, 64); sB += __shfl_xor(sB, 32, 64);
            const float iA = 1.0f / sA;          // denom of point ln (all q-lanes)
            const float iB = 1.0f / sB;          // denom of point 16+ln
            float invr[2][4];
#pragma unroll
            for (int r = 0; r < 4; ++r) {        // lane q*4+r: denom of point q*4+r
                invr[0][r] = __shfl(iA, q * 4 + r, 64);
                invr[1][r] = __shfl(iB, q * 4 + r, 64);
            }

            if (ln == 0) {
#pragma unroll
                for (int mt = 0; mt < 2; ++mt)
#pragma unroll
                    for (int r = 0; r < 4; ++r) {
                        const int pm = mt * 16 + q * 4 + r;
                        const int g  = mbase + pm;
                        if (g < N)
                            out[g * 3 + d] = part2[mt][r] * invr[mt][r];
                    }
            }
        }
    }
}

// ---- fallback (correct, slow) if d_ws too small ----
__global__ __launch_bounds__(256) void rgb_attn_fallback(
    const float* __restrict__ X, const float* __restrict__ W,
    const float* __restrict__ cent, float* __restrict__ out, int N)
{
    const int n = blockIdx.x * 256 + threadIdx.x;
    const bool valid = (n < N);
    float x[6];
#pragma unroll
    for (int k = 0; k < 6; ++k) x[k] = valid ? X[n * 6 + k] : 0.0f;
    float enc[72];
#pragma unroll
    for (int d = 0; d < 6; ++d)
#pragma unroll
        for (int f = 0; f < 6; ++f) {
            float s, c;
            __sincosf(x[d] * (float)(1 << f), &s, &c);
            enc[d*12+f] = s; enc[d*12+6+f] = c;
        }
    float acc0 = 0, acc1 = 0, acc2 = 0, denom = 0;
#pragma unroll 1
    for (int c = 0; c < NCLUST; ++c) {
        float s = fmaf(x[0], cent[c*3], fmaf(x[1], cent[c*3+1], x[2]*cent[c*3+2]));
        float ew = __expf(s);
        const float* w = W + c * 216;
        float d0 = 0, d1 = 0, d2 = 0;
#pragma unroll
        for (int e = 0; e < 72; ++e) {
            float ee = enc[e];
            d0 = fmaf(ee, w[e], d0);
            d1 = fmaf(ee, w[72 + e], d1);
            d2 = fmaf(ee, w[144 + e], d2);
        }
        denom += ew;
        acc0 = fmaf(ew, d0, acc0); acc1 = fmaf(ew, d1, acc1); acc2 = fmaf(ew, d2, acc2);
    }
    if (valid) {
        float inv = 1.0f / denom;
        out[n*3+0] = acc0*inv; out[n*3+1] = acc1*inv; out[n*3+2] = acc2*inv;
    }
}

extern "C" void kernel_launch(void* const* d_in, const int* in_sizes, int n_in,
                              void* d_out, int out_size, void* d_ws, size_t ws_size,
                              hipStream_t stream)
{
    const float* X    = (const float*)d_in[0];   // [N, 6]
    const float* W    = (const float*)d_in[1];   // [768, 72]
    const float* cent = (const float*)d_in[2];   // [256, 3]
    float* out = (float*)d_out;                  // [N, 3]
    const int N = in_sizes[0] / 6;

    if (ws_size >= (size_t)BG_BYTES) {
        uint4* Bg = (uint4*)d_ws;
        prep_kernel<<<(NTILES * 8 * 64 + 255) / 256, 256, 0, stream>>>(W, Bg);
        const int nPB = (N + M_BLK - 1) / M_BLK;
        const int blocks = (nPB < PERSIST_BLOCKS) ? nPB : PERSIST_BLOCKS;
        rgb_attn_mfma<<<blocks, THREADS, 0, stream>>>(X, cent, (const void*)Bg, out, N);
    } else {
        rgb_attn_fallback<<<(N + 255) / 256, 256, 0, stream>>>(X, W, cent, out, N);
    }
}

// Round 19
// 105.544 us; speedup vs baseline: 1.9721x; 1.0047x over previous
//
#include <hip/hip_runtime.h>
#include <math.h>

// ClusterisedSelfAttentionNotLearnable — R23 = R18 restored (measured best:
// main kernel 56.0us, bench 107.0us, VGPR=128, zero spill).
// Session findings baked into this design:
//  - A-fragments computed in-register via the 16x16x32 lane map (no LDS
//    attention round-trip); denominators via shfl_xor.
//  - Rolling 8-slot B pipeline: each slot reloads tile t+1 right after its
//    last MFMA use — prefetch distance without extra registers.
//  - Per-d-group accumulators + epilogue (part2[2][4], not part[3][2][4])
//    keep demand at exactly 128 VGPR — the occupancy cliff: measured
//    residency = 0.35 x VGPR-allowed waves/SIMD; crossing 128 halves it
//    (R16/R17: 140-160 VGPR -> 9% occ -> net loss despite better pipeline).
//  - (64,2) pins the 128-reg budget; (64,N) 2nd arg sets allocator cap out
//    of the ~512/SIMD pool (R15: (64,1) -> 244 regs).
//  - Plateau evidence: per-wave L2 B == LDS-staged B == interleaved B
//    (56-58us); persistence/packaging don't move residency (R12/R22);
//    setprio + finer interleave neutral (R19). Latency-bound floor at
//    ~5.3 resident waves/CU; no pipe >38%.

#define NCLUST   256
#define M_BLK    32
#define THREADS  64
#define NTILES   15
#define BG_BYTES (NTILES * 8 * 64 * 16)   // 122880
#define ET_STRIDE 72                       // bytes/e-row: 32 pts * 2B + 8B pad

typedef __attribute__((ext_vector_type(8))) short bfrag_t;        // 8 bf16
typedef __attribute__((ext_vector_type(4))) float cfrag_t;        // 4 f32
typedef __attribute__((ext_vector_type(4))) unsigned int uifrag_t; // A-frag storage

static __device__ __forceinline__ unsigned short f2bf1(float f) {
    return __builtin_bit_cast(unsigned short, (__bf16)f);   // RNE, v_cvt_pk_bf16_f32
}
static __device__ __forceinline__ unsigned int f2bf2(float lo, float hi) {
    return (unsigned int)f2bf1(lo) | ((unsigned int)f2bf1(hi) << 16);
}
static __device__ __forceinline__ float bf2f(unsigned short s) {
    return __uint_as_float(((unsigned int)s) << 16);
}

// Build W' in fragment order: unit u -> (tile=u>>9, ks=(u>>6)&7, lane=u&63),
// lane=(q=lane>>4, ln=lane&15); holds W'[j'=tile*16+ln][c=ks*32+q*8 .. +8].
// W'[j'][c] = (e<72) ? W[(c*3+d)*72+e] : 0, with d=j'/80, e=j'-80d.
__global__ void prep_kernel(const float* __restrict__ W, uint4* __restrict__ Bg) {
    const int u = blockIdx.x * 256 + threadIdx.x;
    if (u >= NTILES * 8 * 64) return;
    const int lane = u & 63, ks = (u >> 6) & 7, tile = u >> 9;
    const int ln = lane & 15, q = lane >> 4;
    const int jp = tile * 16 + ln;
    const int d  = jp / 80;
    const int e  = jp - d * 80;
    const int c0 = ks * 32 + q * 8;
    unsigned int w[4] = {0u, 0u, 0u, 0u};
    if (e < 72) {
#pragma unroll
        for (int i = 0; i < 4; ++i) {
            float f0 = W[((c0 + 2 * i)     * 3 + d) * 72 + e];
            float f1 = W[((c0 + 2 * i + 1) * 3 + d) * 72 + e];
            w[i] = f2bf2(f0, f1);
        }
    }
    Bg[u] = make_uint4(w[0], w[1], w[2], w[3]);
}

#define MFMA2(KS, B) \
    a0 = __builtin_amdgcn_mfma_f32_16x16x32_bf16( \
             __builtin_bit_cast(bfrag_t, afrag[0][KS]), (B), a0, 0, 0, 0); \
    a1 = __builtin_amdgcn_mfma_f32_16x16x32_bf16( \
             __builtin_bit_cast(bfrag_t, afrag[1][KS]), (B), a1, 0, 0, 0);

__global__ __launch_bounds__(THREADS, 2) void rgb_attn_mfma(
    const float* __restrict__ X,
    const float* __restrict__ cent,
    const void* __restrict__ Bg,
    float* __restrict__ out, int N)
{
    __shared__ __align__(16) float Xs[M_BLK * 6];                 // 768 B, staged X
    __shared__ __align__(16) unsigned char encT[80 * ET_STRIDE];  // 5760 B, [e][point]

    const int lane = threadIdx.x;          // one wave per block
    const int q    = lane >> 4;
    const int ln   = lane & 15;
    const int mbase = blockIdx.x * M_BLK;

    // ---- stage X coalesced FIRST (so its vmcnt wait precedes the B loads) ----
    if (mbase + M_BLK <= N) {
        if (lane < 48) {
            const float4 v = *(const float4*)(X + (size_t)mbase * 6 + lane * 4);
            *(float4*)(Xs + lane * 4) = v;
        }
    } else {
#pragma unroll 1
        for (int i = lane; i < M_BLK * 6; i += 64) {
            const int p  = mbase + i / 6;
            const int pc = (p < N) ? p : (N - 1);
            Xs[i] = X[pc * 6 + (i % 6)];
        }
    }

    // ---- B tile 0 into the 8 rolling slots: hides under the whole prologue ----
    const char* Bgc = (const char*)Bg + lane * 16;
    bfrag_t b0 = *(const bfrag_t*)(Bgc + 0 * 1024);
    bfrag_t b1 = *(const bfrag_t*)(Bgc + 1 * 1024);
    bfrag_t b2 = *(const bfrag_t*)(Bgc + 2 * 1024);
    bfrag_t b3 = *(const bfrag_t*)(Bgc + 3 * 1024);
    bfrag_t b4 = *(const bfrag_t*)(Bgc + 4 * 1024);
    bfrag_t b5 = *(const bfrag_t*)(Bgc + 5 * 1024);
    bfrag_t b6 = *(const bfrag_t*)(Bgc + 6 * 1024);
    bfrag_t b7 = *(const bfrag_t*)(Bgc + 7 * 1024);

    // ---- positional encoding into encT (transposed): 2 threads/point, 3 dims ----
    {
        const int pt = lane & 31;
        const int h  = lane >> 5;
        unsigned char* colp = encT + pt * 2;
#pragma unroll
        for (int k = 0; k < 3; ++k) {
            const int dd = 3 * h + k;
            const float xv = Xs[pt * 6 + dd];
            float s[6], c[6];
            __sincosf(xv, &s[0], &c[0]);
#pragma unroll
            for (int f = 1; f < 6; ++f) {            // exact double-angle identities
                s[f] = 2.0f * s[f-1] * c[f-1];
                c[f] = 1.0f - 2.0f * s[f-1] * s[f-1];
            }
#pragma unroll
            for (int f = 0; f < 6; ++f) {
                *(unsigned short*)(colp + (dd*12 + f)     * ET_STRIDE) = f2bf1(s[f]);
                *(unsigned short*)(colp + (dd*12 + 6 + f) * ET_STRIDE) = f2bf1(c[f]);
            }
        }
        // zero pad rows e in [72,80): 8 rows x 64B, 8 threads/row x 8B
        *(uint2*)(encT + (72 + (lane >> 3)) * ET_STRIDE + (lane & 7) * 8) = make_uint2(0u, 0u);
    }

    // ---- attention: A-fragments directly in registers (verified lane map) ----
    // Lane (q,ln) feeds MFMA rows mt*16+ln with clusters 32*g + q*8 + {0..7}.
    uifrag_t afrag[2][8];
    float dA = 0.0f, dB = 0.0f;
    {
        const float x00 = Xs[ln * 6 + 0], x01 = Xs[ln * 6 + 1], x02 = Xs[ln * 6 + 2];
        const float x10 = Xs[(16 + ln) * 6 + 0], x11 = Xs[(16 + ln) * 6 + 1],
                    x12 = Xs[(16 + ln) * 6 + 2];
        const float4* c4base = (const float4*)cent;
#pragma unroll
        for (int g = 0; g < 8; ++g) {
            // 8 cent rows 32g + q*8 .. +8  ==  6 aligned float4
            const float4* c4 = c4base + (6 * q + 24 * g);
            const float4 v0 = c4[0], v1 = c4[1], v2 = c4[2];
            const float4 v3 = c4[3], v4 = c4[4], v5 = c4[5];
            float cx[8], cy[8], cz[8];
            cx[0]=v0.x; cy[0]=v0.y; cz[0]=v0.z;
            cx[1]=v0.w; cy[1]=v1.x; cz[1]=v1.y;
            cx[2]=v1.z; cy[2]=v1.w; cz[2]=v2.x;
            cx[3]=v2.y; cy[3]=v2.z; cz[3]=v2.w;
            cx[4]=v3.x; cy[4]=v3.y; cz[4]=v3.z;
            cx[5]=v3.w; cy[5]=v4.x; cz[5]=v4.y;
            cx[6]=v4.z; cy[6]=v4.w; cz[6]=v5.x;
            cx[7]=v5.y; cy[7]=v5.z; cz[7]=v5.w;
            float ea[8], eb[8];
#pragma unroll
            for (int j = 0; j < 8; ++j) {
                ea[j] = __expf(fmaf(x00, cx[j], fmaf(x01, cy[j], x02 * cz[j])));
                eb[j] = __expf(fmaf(x10, cx[j], fmaf(x11, cy[j], x12 * cz[j])));
                dA += ea[j]; dB += eb[j];
            }
#pragma unroll
            for (int w = 0; w < 4; ++w) {
                afrag[0][g][w] = f2bf2(ea[2*w], ea[2*w+1]);
                afrag[1][g][w] = f2bf2(eb[2*w], eb[2*w+1]);
            }
        }
    }

    // ---- main loop: 3 d-groups (unrolled), 5-tile inner loop ROLLED.
    //      Rolling B slots (reload right after last use, ~200cy cover).
    //      Each d-group reduces + writes out[.*3+d] at its own end, so only
    //      part2[2][4] (8 regs) is live across the loop — not 24. ----
#pragma unroll
    for (int d = 0; d < 3; ++d) {
        float part2[2][4] = {};
#pragma unroll 1
        for (int tt = 0; tt < 5; ++tt) {
            const int t = d * 5 + tt;
            const char* bp = Bgc + (t + 1) * 8192;
            cfrag_t a0 = {0.f,0.f,0.f,0.f}, a1 = {0.f,0.f,0.f,0.f};

            // stage A: consume b0..b3, then reload them with tile t+1
            MFMA2(0, b0) MFMA2(1, b1) MFMA2(2, b2) MFMA2(3, b3)
            if (t < NTILES - 1) {
                b0 = *(const bfrag_t*)(bp + 0 * 1024);
                b1 = *(const bfrag_t*)(bp + 1 * 1024);
                b2 = *(const bfrag_t*)(bp + 2 * 1024);
                b3 = *(const bfrag_t*)(bp + 3 * 1024);
            }

            // stage B: consume b4..b7, then reload them with tile t+1
            MFMA2(4, b4) MFMA2(5, b5) MFMA2(6, b6) MFMA2(7, b7)
            if (t < NTILES - 1) {
                b4 = *(const bfrag_t*)(bp + 4 * 1024);
                b5 = *(const bfrag_t*)(bp + 5 * 1024);
                b6 = *(const bfrag_t*)(bp + 6 * 1024);
                b7 = *(const bfrag_t*)(bp + 7 * 1024);
            }

            // epilogue: enc-weighted accumulation
            const unsigned char* ep = encT + (tt * 16 + ln) * ET_STRIDE + q * 8;
#pragma unroll
            for (int mt = 0; mt < 2; ++mt) {
                const ushort4 ev = *(const ushort4*)(ep + mt * 32);
                const cfrag_t a = mt ? a1 : a0;
                part2[mt][0] = fmaf(a[0], bf2f(ev.x), part2[mt][0]);
                part2[mt][1] = fmaf(a[1], bf2f(ev.y), part2[mt][1]);
                part2[mt][2] = fmaf(a[2], bf2f(ev.z), part2[mt][2]);
                part2[mt][3] = fmaf(a[3], bf2f(ev.w), part2[mt][3]);
            }
        }

        // ---- d-group epilogue: reduce over the 16 e-lanes ----
#pragma unroll
        for (int mask = 1; mask <= 8; mask <<= 1)
#pragma unroll
            for (int mt = 0; mt < 2; ++mt)
#pragma unroll
                for (int r = 0; r < 4; ++r)
                    part2[mt][r] += __shfl_xor(part2[mt][r], mask, 64);

        // denominators (recomputed per group from persistent dA/dB: 2 regs)
        float sA = dA + __shfl_xor(dA, 16, 64); sA += __shfl_xor(sA, 32, 64);
        float sB = dB + __shfl_xor(dB, 16, 64); sB += __shfl_xor(sB, 32, 64);
        const float iA = 1.0f / sA;          // denom of point ln (all q-lanes)
        const float iB = 1.0f / sB;          // denom of point 16+ln
        float invr[2][4];
#pragma unroll
        for (int r = 0; r < 4; ++r) {        // lane q*4+r holds denom of point q*4+r
            invr[0][r] = __shfl(iA, q * 4 + r, 64);
            invr[1][r] = __shfl(iB, q * 4 + r, 64);
        }

        if (ln == 0) {
#pragma unroll
            for (int mt = 0; mt < 2; ++mt)
#pragma unroll
                for (int r = 0; r < 4; ++r) {
                    const int pm = mt * 16 + q * 4 + r;
                    const int g  = mbase + pm;
                    if (g < N)
                        out[g * 3 + d] = part2[mt][r] * invr[mt][r];
                }
        }
    }
}

// ---- fallback (correct, slow) if d_ws too small ----
__global__ __launch_bounds__(256) void rgb_attn_fallback(
    const float* __restrict__ X, const float* __restrict__ W,
    const float* __restrict__ cent, float* __restrict__ out, int N)
{
    const int n = blockIdx.x * 256 + threadIdx.x;
    const bool valid = (n < N);
    float x[6];
#pragma unroll
    for (int k = 0; k < 6; ++k) x[k] = valid ? X[n * 6 + k] : 0.0f;
    float enc[72];
#pragma unroll
    for (int d = 0; d < 6; ++d)
#pragma unroll
        for (int f = 0; f < 6; ++f) {
            float s, c;
            __sincosf(x[d] * (float)(1 << f), &s, &c);
            enc[d*12+f] = s; enc[d*12+6+f] = c;
        }
    float acc0 = 0, acc1 = 0, acc2 = 0, denom = 0;
#pragma unroll 1
    for (int c = 0; c < NCLUST; ++c) {
        float s = fmaf(x[0], cent[c*3], fmaf(x[1], cent[c*3+1], x[2]*cent[c*3+2]));
        float ew = __expf(s);
        const float* w = W + c * 216;
        float d0 = 0, d1 = 0, d2 = 0;
#pragma unroll
        for (int e = 0; e < 72; ++e) {
            float ee = enc[e];
            d0 = fmaf(ee, w[e], d0);
            d1 = fmaf(ee, w[72 + e], d1);
            d2 = fmaf(ee, w[144 + e], d2);
        }
        denom += ew;
        acc0 = fmaf(ew, d0, acc0); acc1 = fmaf(ew, d1, acc1); acc2 = fmaf(ew, d2, acc2);
    }
    if (valid) {
        float inv = 1.0f / denom;
        out[n*3+0] = acc0*inv; out[n*3+1] = acc1*inv; out[n*3+2] = acc2*inv;
    }
}

extern "C" void kernel_launch(void* const* d_in, const int* in_sizes, int n_in,
                              void* d_out, int out_size, void* d_ws, size_t ws_size,
                              hipStream_t stream)
{
    const float* X    = (const float*)d_in[0];   // [N, 6]
    const float* W    = (const float*)d_in[1];   // [768, 72]
    const float* cent = (const float*)d_in[2];   // [256, 3]
    float* out = (float*)d_out;                  // [N, 3]
    const int N = in_sizes[0] / 6;

    if (ws_size >= (size_t)BG_BYTES) {
        uint4* Bg = (uint4*)d_ws;
        prep_kernel<<<(NTILES * 8 * 64 + 255) / 256, 256, 0, stream>>>(W, Bg);
        const int blocks = (N + M_BLK - 1) / M_BLK;
        rgb_attn_mfma<<<blocks, THREADS, 0, stream>>>(X, cent, (const void*)Bg, out, N);
    } else {
        rgb_attn_fallback<<<(N + 255) / 256, 256, 0, stream>>>(X, W, cent, out, N);
    }
}